// Round 3
// baseline (240.251 us; speedup 1.0000x reference)
//
#include <hip/hip_runtime.h>

// RoPE, interleaved-pair convention:
//   out[2k]   = x[2k]*cos[pos][k] - x[2k+1]*sin[pos][k]
//   out[2k+1] = x[2k]*sin[pos][k] + x[2k+1]*cos[pos][k]
// x: (B,H,S,128) fp32 contiguous.
// 16 threads per row; each thread handles 4 pairs = 8 floats = 32 B.
// Streaming x/out use nontemporal hints so the sin/cos tables stay
// L2-resident; table loads are 16 B coalesced and cache normally.
// NOTE: __builtin_nontemporal_* requires a native clang vector type,
// not HIP_vector_type — hence nat_float4.

typedef float nat_float4 __attribute__((ext_vector_type(4)));

template <bool POW2>
__global__ __launch_bounds__(256) void rope_kernel(
    const nat_float4* __restrict__ x,
    const float4* __restrict__ sin_c,   // (MAX_SEQ_LEN, 64) -> (.., 16) float4
    const float4* __restrict__ cos_c,
    const int*    __restrict__ tok_pos, // (S,)
    nat_float4*   __restrict__ out,
    int n8, int s_div)                  // n8 = elements/8; s_div = S-1 (mask) or S
{
    int idx = blockIdx.x * blockDim.x + threadIdx.x;
    if (idx >= n8) return;

    int row = idx >> 4;      // (b,h,s) row; 16 threads per row
    int j   = idx & 15;      // covers pairs 4j..4j+3  (floats 8j..8j+7)
    int s   = POW2 ? (row & s_div) : (row % s_div);
    int p   = tok_pos[s];

    float4 c  = cos_c[p * 16 + j];   // cos[p][4j..4j+3]
    float4 sn = sin_c[p * 16 + j];

    const nat_float4* xp = x + (row << 5) + (j << 1);   // float4 index: row*32 + 2j
    nat_float4 v0 = __builtin_nontemporal_load(xp);
    nat_float4 v1 = __builtin_nontemporal_load(xp + 1);

    nat_float4 o0, o1;
    o0.x = v0.x * c.x - v0.y * sn.x;
    o0.y = v0.x * sn.x + v0.y * c.x;
    o0.z = v0.z * c.y - v0.w * sn.y;
    o0.w = v0.z * sn.y + v0.w * c.y;
    o1.x = v1.x * c.z - v1.y * sn.z;
    o1.y = v1.x * sn.z + v1.y * c.z;
    o1.z = v1.z * c.w - v1.w * sn.w;
    o1.w = v1.z * sn.w + v1.w * c.w;

    nat_float4* op = out + (row << 5) + (j << 1);
    __builtin_nontemporal_store(o0, op);
    __builtin_nontemporal_store(o1, op + 1);
}

extern "C" void kernel_launch(void* const* d_in, const int* in_sizes, int n_in,
                              void* d_out, int out_size, void* d_ws, size_t ws_size,
                              hipStream_t stream) {
    // setup_inputs order: x, sin_cached, cos_cached, token_positions
    const nat_float4* x     = (const nat_float4*)d_in[0];
    const float4*     sin_c = (const float4*)d_in[1];
    const float4*     cos_c = (const float4*)d_in[2];
    const int*        tpos  = (const int*)d_in[3];
    nat_float4*       out   = (nat_float4*)d_out;

    const int S  = in_sizes[3];       // 4096
    const int n8 = out_size / 8;      // one thread per 8 floats

    const int block = 256;
    const int grid  = (n8 + block - 1) / block;

    if ((S & (S - 1)) == 0) {
        rope_kernel<true><<<grid, block, 0, stream>>>(x, sin_c, cos_c, tpos, out, n8, S - 1);
    } else {
        rope_kernel<false><<<grid, block, 0, stream>>>(x, sin_c, cos_c, tpos, out, n8, S);
    }
}

// Round 4
// 228.043 us; speedup vs baseline: 1.0535x; 1.0535x over previous
//
#include <hip/hip_runtime.h>

// RoPE, interleaved-pair convention:
//   out[2k]   = x[2k]*cos[pos][k] - x[2k+1]*sin[pos][k]
//   out[2k+1] = x[2k]*sin[pos][k] + x[2k+1]*cos[pos][k]
// x: (B,H,S,128) fp32 contiguous. One thread per float4 (2 pairs), 32
// threads per row: every global load/store instruction covers a fully
// contiguous, fully-used 1 KiB span -> safe for nontemporal hints.
// nt on the x/out streams keeps the ~2 MB hot sin/cos rows L2-resident;
// table loads cache normally.
// NOTE: __builtin_nontemporal_* needs a native clang vector type.

typedef float nat_float4 __attribute__((ext_vector_type(4)));

template <bool POW2>
__global__ __launch_bounds__(256) void rope_kernel(
    const nat_float4* __restrict__ x,
    const float2* __restrict__ sin_c,   // (MAX_SEQ_LEN, 64) -> (.., 32) float2
    const float2* __restrict__ cos_c,
    const int*    __restrict__ tok_pos, // (S,)
    nat_float4*   __restrict__ out,
    int n4, int s_div)                  // s_div = S-1 (mask) if POW2 else S
{
    int idx = blockIdx.x * blockDim.x + threadIdx.x;
    if (idx >= n4) return;

    int row = idx >> 5;      // which (b,h,s) row; 32 float4 per row
    int j   = idx & 31;      // float4 within row -> pairs 2j, 2j+1
    int s   = POW2 ? (row & s_div) : (row % s_div);
    int p   = tok_pos[s];

    float2 c  = cos_c[p * 32 + j];  // cos row: 64 floats = 32 float2
    float2 sn = sin_c[p * 32 + j];

    nat_float4 v = __builtin_nontemporal_load(x + idx);
    nat_float4 o;
    o.x = v.x * c.x - v.y * sn.x;
    o.y = v.x * sn.x + v.y * c.x;
    o.z = v.z * c.y - v.w * sn.y;
    o.w = v.z * sn.y + v.w * c.y;
    __builtin_nontemporal_store(o, out + idx);
}

extern "C" void kernel_launch(void* const* d_in, const int* in_sizes, int n_in,
                              void* d_out, int out_size, void* d_ws, size_t ws_size,
                              hipStream_t stream) {
    // setup_inputs order: x, sin_cached, cos_cached, token_positions
    const nat_float4* x     = (const nat_float4*)d_in[0];
    const float2*     sin_c = (const float2*)d_in[1];
    const float2*     cos_c = (const float2*)d_in[2];
    const int*        tpos  = (const int*)d_in[3];
    nat_float4*       out   = (nat_float4*)d_out;

    const int S  = in_sizes[3];       // 4096
    const int n4 = out_size / 4;      // one thread per float4

    const int block = 256;
    const int grid  = (n4 + block - 1) / block;

    if ((S & (S - 1)) == 0) {
        rope_kernel<true><<<grid, block, 0, stream>>>(x, sin_c, cos_c, tpos, out, n4, S - 1);
    } else {
        rope_kernel<false><<<grid, block, 0, stream>>>(x, sin_c, cos_c, tpos, out, n4, S);
    }
}